// Round 2
// baseline (2587.550 us; speedup 1.0000x reference)
//
#include <hip/hip_runtime.h>
#include <hip/hip_bf16.h>

#define TOK 8192
#define DM 384
#define QKD 48
#define EM 768
#define NBLK 8
#define NVOCAB 100
#define SEQ 2048
#define HN 1664
#define HNV 1632

using short8 = __attribute__((ext_vector_type(8))) short;
using f32x4  = __attribute__((ext_vector_type(4))) float;

static __device__ __forceinline__ float bf2f(short s) {
    union { unsigned u; float f; } c; c.u = ((unsigned)(unsigned short)s) << 16; return c.f;
}
static __device__ __forceinline__ short f2bf(float f) {
    union { float f; unsigned u; } c; c.f = f;
    unsigned r = (c.u + 0x7FFFu + ((c.u >> 16) & 1u)) >> 16;
    return (short)r;
}

// ---------- weight conversion ----------
__global__ void k_cvt(const float* __restrict__ s, short* __restrict__ d, int n) {
    for (int i = blockIdx.x * 256 + threadIdx.x; i < n; i += gridDim.x * 256)
        d[i] = f2bf(s[i]);
}
__global__ void k_cvt_expw(const float* __restrict__ s, short* __restrict__ d) {
    const int n = NBLK * HN * DM;
    for (int i = blockIdx.x * 256 + threadIdx.x; i < n; i += gridDim.x * 256) {
        int L = i / (HN * DM); int rem = i % (HN * DM);
        int r = rem / DM; int c = rem % DM;
        float v = (r < HNV) ? s[((size_t)L * HNV + r) * DM + c] : 0.f;
        d[i] = f2bf(v);
    }
}
__global__ void k_cvt_outw(const float* __restrict__ s, short* __restrict__ d) {
    const int n = 128 * DM;
    for (int i = blockIdx.x * 256 + threadIdx.x; i < n; i += gridDim.x * 256) {
        int r = i / DM, c = i % DM;
        d[i] = f2bf(r < NVOCAB ? s[r * DM + c] : 0.f);
    }
}

// ---------- embedding + initial LN ----------
__global__ __launch_bounds__(256) void k_embed(const int* __restrict__ q,
        const float* __restrict__ freqs, const float* __restrict__ lng,
        const float* __restrict__ lnb, float* __restrict__ x) {
    int wid = blockIdx.x * 4 + (threadIdx.x >> 6);
    int lane = threadIdx.x & 63;
    if (wid >= TOK) return;
    float qv = (float)q[wid];
    float v[6]; float s = 0.f, s2 = 0.f;
    #pragma unroll
    for (int i = 0; i < 6; ++i) {
        int d = lane + 64 * i;
        float val;
        if (d < 192) val = sinf(qv * freqs[d]);
        else         val = cosf(qv * freqs[d - 192]);
        v[i] = val; s += val; s2 += val * val;
    }
    #pragma unroll
    for (int m = 1; m < 64; m <<= 1) { s += __shfl_xor(s, m); s2 += __shfl_xor(s2, m); }
    float mean = s * (1.f / DM);
    float var = s2 * (1.f / DM) - mean * mean;
    float rstd = rsqrtf(var + 1e-5f);
    float* xr = x + (size_t)wid * DM;
    #pragma unroll
    for (int i = 0; i < 6; ++i) {
        int d = lane + 64 * i;
        xr[d] = (v[i] - mean) * rstd * lng[d] + lnb[d];
    }
}

// ---------- LayerNorm fp32 -> bf16 ----------
__global__ __launch_bounds__(256) void k_ln(const float* __restrict__ x,
        const float* __restrict__ g, const float* __restrict__ b,
        short* __restrict__ xn) {
    int wid = blockIdx.x * 4 + (threadIdx.x >> 6);
    int lane = threadIdx.x & 63;
    if (wid >= TOK) return;
    const float* xr = x + (size_t)wid * DM;
    float v[6]; float s = 0.f, s2 = 0.f;
    #pragma unroll
    for (int i = 0; i < 6; ++i) {
        v[i] = xr[lane + 64 * i]; s += v[i]; s2 += v[i] * v[i];
    }
    #pragma unroll
    for (int m = 1; m < 64; m <<= 1) { s += __shfl_xor(s, m); s2 += __shfl_xor(s2, m); }
    float mean = s * (1.f / DM);
    float var = s2 * (1.f / DM) - mean * mean;
    float rstd = rsqrtf(var + 1e-5f);
    short* xo = xn + (size_t)wid * DM;
    #pragma unroll
    for (int i = 0; i < 6; ++i) {
        int d = lane + 64 * i;
        xo[d] = f2bf((v[i] - mean) * rstd * g[d] + b[d]);
    }
}

// ---------- GEMM: C[M,N] = A[M,K] @ Bw[N,K]^T, bf16 in, fp32 acc ----------
// Staging: each thread loads 16 shorts (two short8) -> full 128x32 tile.
// MODE 0: store bf16 to Cp (stride ldc)
// MODE 1: add fp32 into Cp (stride ldc)
// MODE 2: store fp32 with col < NVOCAB guard, stride NVOCAB
template<int MODE>
__global__ __launch_bounds__(256) void k_gemm(const short* __restrict__ A,
        const short* __restrict__ Bw, int K, int lda, int ldb,
        void* __restrict__ Cp, int ldc) {
    __shared__ __align__(16) short As[128 * 40];
    __shared__ __align__(16) short Bs[128 * 40];
    int m0 = blockIdx.x * 128, n0 = blockIdx.y * 128;
    int t = threadIdx.x;
    int wid = t >> 6, lane = t & 63;
    int wm = (wid >> 1) * 64, wn = (wid & 1) * 64;
    int lr = lane & 15, lk = (lane >> 4) * 8;
    int sr = t >> 1, sc = (t & 1) * 16;
    const f32x4 vz = {0.f, 0.f, 0.f, 0.f};
    f32x4 acc[4][4];
    #pragma unroll
    for (int i = 0; i < 4; ++i)
        #pragma unroll
        for (int j = 0; j < 4; ++j) acc[i][j] = vz;
    const short* Arow = A + (size_t)(m0 + sr) * lda + sc;
    const short* Brow = Bw + (size_t)(n0 + sr) * ldb + sc;
    for (int k0 = 0; k0 < K; k0 += 32) {
        if (k0) __syncthreads();
        *(short8*)(As + sr * 40 + sc)     = *(const short8*)(Arow + k0);
        *(short8*)(As + sr * 40 + sc + 8) = *(const short8*)(Arow + k0 + 8);
        *(short8*)(Bs + sr * 40 + sc)     = *(const short8*)(Brow + k0);
        *(short8*)(Bs + sr * 40 + sc + 8) = *(const short8*)(Brow + k0 + 8);
        __syncthreads();
        short8 af[4], bfr[4];
        #pragma unroll
        for (int i = 0; i < 4; ++i) {
            af[i]  = *(const short8*)(As + (wm + i * 16 + lr) * 40 + lk);
            bfr[i] = *(const short8*)(Bs + (wn + i * 16 + lr) * 40 + lk);
        }
        #pragma unroll
        for (int i = 0; i < 4; ++i)
            #pragma unroll
            for (int j = 0; j < 4; ++j)
                acc[i][j] = __builtin_amdgcn_mfma_f32_16x16x32_bf16(af[i], bfr[j], acc[i][j], 0, 0, 0);
    }
    int rb = m0 + wm + (lane >> 4) * 4;
    int cb = n0 + wn + lr;
    #pragma unroll
    for (int i = 0; i < 4; ++i)
        #pragma unroll
        for (int j = 0; j < 4; ++j)
            #pragma unroll
            for (int r = 0; r < 4; ++r) {
                int row = rb + i * 16 + r;
                int col = cb + j * 16;
                float v = acc[i][j][r];
                if (MODE == 0) ((short*)Cp)[(size_t)row * ldc + col] = f2bf(v);
                else if (MODE == 1) ((float*)Cp)[(size_t)row * ldc + col] += v;
                else if (col < NVOCAB) ((float*)Cp)[(size_t)row * NVOCAB + col] = v;
            }
}

// ---------- geglu + qk extraction + V transpose ----------
__global__ __launch_bounds__(256) void k_geglu(const short* __restrict__ h,
        short* __restrict__ cat, short* __restrict__ vT,
        short* __restrict__ qhb, short* __restrict__ khb) {
    __shared__ short vl[64 * 390];
    int tb = blockIdx.x * 64;
    int t = threadIdx.x;
    for (int i = t; i < 64 * 64; i += 256) {
        int row = i >> 6, f = i & 63;
        size_t tok = tb + row;
        short qv = 0, kv = 0;
        if (f < QKD) { qv = h[tok * HN + f]; kv = h[tok * HN + QKD + f]; }
        qhb[tok * 64 + f] = qv;
        khb[tok * 64 + f] = kv;
    }
    for (int i = t; i < 64 * EM; i += 256) {
        int row = i / EM, e = i % EM;
        size_t tok = tb + row;
        float lin = bf2f(h[tok * HN + 2 * QKD + e]);
        float pg  = bf2f(h[tok * HN + 2 * QKD + EM + e]);
        float gel = pg * 0.5f * (1.f + erff(pg * 0.70710678118654752f));
        short bv = f2bf(lin * gel);
        if (e < DM) cat[tok * EM + e] = bv;
        else vl[row * 390 + (e - DM)] = bv;
    }
    __syncthreads();
    for (int i = t; i < DM * 64; i += 256) {
        int feat = i >> 6, tok = i & 63;
        vT[(size_t)feat * TOK + tb + tok] = vl[tok * 390 + feat];
    }
}

// ---------- flash attention: 1 q-tile (16 rows) per block, 4 waves split V-features ----------
__global__ __launch_bounds__(256) void k_flash(const short* __restrict__ qhb,
        const short* __restrict__ khb, const short* __restrict__ vT,
        short* __restrict__ cat) {
    __shared__ __align__(16) short Pbuf[4 * 16 * 40];
    int bid = blockIdx.x;
    int b = bid >> 7, qt = bid & 127;
    int tb = b * SEQ;
    int t = threadIdx.x;
    int wid = t >> 6, lane = t & 63;
    int lr = lane & 15, lg = lane >> 4;
    int q0 = qt * 16;
    short* P = Pbuf + wid * (16 * 40);
    const float scale = 0.14433756729740643f; // 1/sqrt(48)
    const f32x4 vzero = {0.f, 0.f, 0.f, 0.f};

    short8 qf[2];
    #pragma unroll
    for (int ks = 0; ks < 2; ++ks)
        qf[ks] = *(const short8*)(qhb + (size_t)(tb + q0 + lr) * 64 + ks * 32 + lg * 8);

    f32x4 o[6];
    #pragma unroll
    for (int j = 0; j < 6; ++j) o[j] = vzero;
    float mi[4], li[4], al[4];
    #pragma unroll
    for (int r = 0; r < 4; ++r) { mi[r] = -1e30f; li[r] = 0.f; }

    int nkb = (q0 >> 5) + 1;
    for (int kb = 0; kb < nkb; ++kb) {
        int kbase = kb * 32;
        f32x4 s0 = vzero, s1 = vzero;
        #pragma unroll
        for (int ks = 0; ks < 2; ++ks) {
            short8 kf0 = *(const short8*)(khb + (size_t)(tb + kbase + lr) * 64 + ks * 32 + lg * 8);
            short8 kf1 = *(const short8*)(khb + (size_t)(tb + kbase + 16 + lr) * 64 + ks * 32 + lg * 8);
            s0 = __builtin_amdgcn_mfma_f32_16x16x32_bf16(qf[ks], kf0, s0, 0, 0, 0);
            s1 = __builtin_amdgcn_mfma_f32_16x16x32_bf16(qf[ks], kf1, s1, 0, 0, 0);
        }
        #pragma unroll
        for (int r = 0; r < 4; ++r) {
            int qg = q0 + lg * 4 + r;
            float v0 = s0[r] * scale, v1 = s1[r] * scale;
            if (kbase + lr > qg) v0 = -1e30f;
            if (kbase + 16 + lr > qg) v1 = -1e30f;
            float mx = fmaxf(v0, v1);
            #pragma unroll
            for (int d2 = 1; d2 < 16; d2 <<= 1) mx = fmaxf(mx, __shfl_xor(mx, d2));
            float mn = fmaxf(mi[r], mx);
            float p0 = __expf(v0 - mn), p1 = __expf(v1 - mn);
            float sum = p0 + p1;
            #pragma unroll
            for (int d2 = 1; d2 < 16; d2 <<= 1) sum += __shfl_xor(sum, d2);
            float a = __expf(mi[r] - mn);
            li[r] = li[r] * a + sum;
            mi[r] = mn; al[r] = a;
            s0[r] = p0; s1[r] = p1;
        }
        #pragma unroll
        for (int j = 0; j < 6; ++j)
            #pragma unroll
            for (int r = 0; r < 4; ++r) o[j][r] *= al[r];
        __syncthreads();
        #pragma unroll
        for (int r = 0; r < 4; ++r) {
            P[(lg * 4 + r) * 40 + lr] = f2bf(s0[r]);
            P[(lg * 4 + r) * 40 + 16 + lr] = f2bf(s1[r]);
        }
        __syncthreads();
        short8 pf = *(const short8*)(P + lr * 40 + lg * 8);
        #pragma unroll
        for (int j = 0; j < 6; ++j) {
            int ntg = wid * 6 + j;
            short8 vf = *(const short8*)(vT + (size_t)(ntg * 16 + lr) * TOK + tb + kbase + lg * 8);
            o[j] = __builtin_amdgcn_mfma_f32_16x16x32_bf16(pf, vf, o[j], 0, 0, 0);
        }
    }
    float inv[4];
    #pragma unroll
    for (int r = 0; r < 4; ++r) inv[r] = 1.f / li[r];
    #pragma unroll
    for (int j = 0; j < 6; ++j) {
        int ntg = wid * 6 + j;
        #pragma unroll
        for (int r = 0; r < 4; ++r) {
            size_t tok = tb + q0 + lg * 4 + r;
            cat[tok * EM + DM + ntg * 16 + lr] = f2bf(o[j][r] * inv[r]);
        }
    }
}

extern "C" void kernel_launch(void* const* d_in, const int* in_sizes, int n_in,
                              void* d_out, int out_size, void* d_ws, size_t ws_size,
                              hipStream_t stream) {
    const int*   q     = (const int*)d_in[0];
    const float* freqs = (const float*)d_in[1];
    const float* expw  = (const float*)d_in[2];
    const float* projw = (const float*)d_in[3];
    const float* blkg  = (const float*)d_in[4];
    const float* blkb  = (const float*)d_in[5];
    const float* lng   = (const float*)d_in[6];
    const float* lnb   = (const float*)d_in[7];
    const float* outw  = (const float*)d_in[8];
    float* out = (float*)d_out;

    char* p = (char*)d_ws;
    auto alloc = [&](size_t bytes) {
        char* r = p; p += (bytes + 255) & ~(size_t)255; return r;
    };
    float* x   = (float*)alloc((size_t)TOK * DM * 4);
    short* xn  = (short*)alloc((size_t)TOK * DM * 2);
    short* h   = (short*)alloc((size_t)TOK * HN * 2);
    short* cat = (short*)alloc((size_t)TOK * EM * 2);
    short* vT  = (short*)alloc((size_t)DM * TOK * 2);
    short* qhb = (short*)alloc((size_t)TOK * 64 * 2);
    short* khb = (short*)alloc((size_t)TOK * 64 * 2);
    short* ewb = (short*)alloc((size_t)NBLK * HN * DM * 2);
    short* pwb = (short*)alloc((size_t)NBLK * DM * EM * 2);
    short* owb = (short*)alloc((size_t)128 * DM * 2);

    k_cvt_expw<<<2048, 256, 0, stream>>>(expw, ewb);
    k_cvt<<<2048, 256, 0, stream>>>(projw, pwb, NBLK * DM * EM);
    k_cvt_outw<<<192, 256, 0, stream>>>(outw, owb);
    k_embed<<<TOK / 4, 256, 0, stream>>>(q, freqs, lng, lnb, x);

    for (int L = 0; L < NBLK; ++L) {
        k_ln<<<TOK / 4, 256, 0, stream>>>(x, blkg + L * DM, blkb + L * DM, xn);
        k_gemm<0><<<dim3(64, 13), 256, 0, stream>>>(xn, ewb + (size_t)L * HN * DM,
                                                    DM, DM, DM, h, HN);
        k_geglu<<<TOK / 64, 256, 0, stream>>>(h, cat, vT, qhb, khb);
        k_flash<<<512, 256, 0, stream>>>(qhb, khb, vT, cat);
        k_gemm<1><<<dim3(64, 3), 256, 0, stream>>>(cat, pwb + (size_t)L * DM * EM,
                                                   EM, EM, EM, x, DM);
    }
    k_ln<<<TOK / 4, 256, 0, stream>>>(x, lng, lnb, xn);
    k_gemm<2><<<dim3(64, 1), 256, 0, stream>>>(xn, owb, DM, DM, DM, out, NVOCAB);
}

// Round 3
// 2517.941 us; speedup vs baseline: 1.0276x; 1.0276x over previous
//
#include <hip/hip_runtime.h>
#include <hip/hip_bf16.h>

#define TOK 8192
#define DM 384
#define QKD 48
#define EM 768
#define NBLK 8
#define NVOCAB 100
#define SEQ 2048
#define HN 1664
#define HNV 1632

using short8 = __attribute__((ext_vector_type(8))) short;
using f32x4  = __attribute__((ext_vector_type(4))) float;

static __device__ __forceinline__ float bf2f(short s) {
    union { unsigned u; float f; } c; c.u = ((unsigned)(unsigned short)s) << 16; return c.f;
}
static __device__ __forceinline__ short f2bf(float f) {
    union { float f; unsigned u; } c; c.f = f;
    unsigned r = (c.u + 0x7FFFu + ((c.u >> 16) & 1u)) >> 16;
    return (short)r;
}

// ---------- weight conversion ----------
__global__ void k_cvt(const float* __restrict__ s, short* __restrict__ d, int n) {
    for (int i = blockIdx.x * 256 + threadIdx.x; i < n; i += gridDim.x * 256)
        d[i] = f2bf(s[i]);
}
__global__ void k_cvt_expw(const float* __restrict__ s, short* __restrict__ d) {
    const int n = NBLK * HN * DM;
    for (int i = blockIdx.x * 256 + threadIdx.x; i < n; i += gridDim.x * 256) {
        int L = i / (HN * DM); int rem = i % (HN * DM);
        int r = rem / DM; int c = rem % DM;
        float v = (r < HNV) ? s[((size_t)L * HNV + r) * DM + c] : 0.f;
        d[i] = f2bf(v);
    }
}
__global__ void k_cvt_outw(const float* __restrict__ s, short* __restrict__ d) {
    const int n = 128 * DM;
    for (int i = blockIdx.x * 256 + threadIdx.x; i < n; i += gridDim.x * 256) {
        int r = i / DM, c = i % DM;
        d[i] = f2bf(r < NVOCAB ? s[r * DM + c] : 0.f);
    }
}

// ---------- embedding + initial LN ----------
__global__ __launch_bounds__(256) void k_embed(const int* __restrict__ q,
        const float* __restrict__ freqs, const float* __restrict__ lng,
        const float* __restrict__ lnb, float* __restrict__ x) {
    int wid = blockIdx.x * 4 + (threadIdx.x >> 6);
    int lane = threadIdx.x & 63;
    if (wid >= TOK) return;
    float qv = (float)q[wid];
    float v[6]; float s = 0.f, s2 = 0.f;
    #pragma unroll
    for (int i = 0; i < 6; ++i) {
        int d = lane + 64 * i;
        float val;
        if (d < 192) val = sinf(qv * freqs[d]);
        else         val = cosf(qv * freqs[d - 192]);
        v[i] = val; s += val; s2 += val * val;
    }
    #pragma unroll
    for (int m = 1; m < 64; m <<= 1) { s += __shfl_xor(s, m); s2 += __shfl_xor(s2, m); }
    float mean = s * (1.f / DM);
    float var = s2 * (1.f / DM) - mean * mean;
    float rstd = rsqrtf(var + 1e-5f);
    float* xr = x + (size_t)wid * DM;
    #pragma unroll
    for (int i = 0; i < 6; ++i) {
        int d = lane + 64 * i;
        xr[d] = (v[i] - mean) * rstd * lng[d] + lnb[d];
    }
}

// ---------- LayerNorm fp32 -> bf16 ----------
__global__ __launch_bounds__(256) void k_ln(const float* __restrict__ x,
        const float* __restrict__ g, const float* __restrict__ b,
        short* __restrict__ xn) {
    int wid = blockIdx.x * 4 + (threadIdx.x >> 6);
    int lane = threadIdx.x & 63;
    if (wid >= TOK) return;
    const float* xr = x + (size_t)wid * DM;
    float v[6]; float s = 0.f, s2 = 0.f;
    #pragma unroll
    for (int i = 0; i < 6; ++i) {
        v[i] = xr[lane + 64 * i]; s += v[i]; s2 += v[i] * v[i];
    }
    #pragma unroll
    for (int m = 1; m < 64; m <<= 1) { s += __shfl_xor(s, m); s2 += __shfl_xor(s2, m); }
    float mean = s * (1.f / DM);
    float var = s2 * (1.f / DM) - mean * mean;
    float rstd = rsqrtf(var + 1e-5f);
    short* xo = xn + (size_t)wid * DM;
    #pragma unroll
    for (int i = 0; i < 6; ++i) {
        int d = lane + 64 * i;
        xo[d] = f2bf((v[i] - mean) * rstd * g[d] + b[d]);
    }
}

// ---------- GEMM: C[M,N] = A[M,K] @ Bw[N,K]^T, bf16 in, fp32 acc ----------
template<int MODE>
__global__ __launch_bounds__(256) void k_gemm(const short* __restrict__ A,
        const short* __restrict__ Bw, int K, int lda, int ldb,
        void* __restrict__ Cp, int ldc) {
    __shared__ __align__(16) short As[128 * 40];
    __shared__ __align__(16) short Bs[128 * 40];
    int m0 = blockIdx.x * 128, n0 = blockIdx.y * 128;
    int t = threadIdx.x;
    int wid = t >> 6, lane = t & 63;
    int wm = (wid >> 1) * 64, wn = (wid & 1) * 64;
    int lr = lane & 15, lk = (lane >> 4) * 8;
    int sr = t >> 1, sc = (t & 1) * 16;
    const f32x4 vz = {0.f, 0.f, 0.f, 0.f};
    f32x4 acc[4][4];
    #pragma unroll
    for (int i = 0; i < 4; ++i)
        #pragma unroll
        for (int j = 0; j < 4; ++j) acc[i][j] = vz;
    const short* Arow = A + (size_t)(m0 + sr) * lda + sc;
    const short* Brow = Bw + (size_t)(n0 + sr) * ldb + sc;
    for (int k0 = 0; k0 < K; k0 += 32) {
        if (k0) __syncthreads();
        *(short8*)(As + sr * 40 + sc)     = *(const short8*)(Arow + k0);
        *(short8*)(As + sr * 40 + sc + 8) = *(const short8*)(Arow + k0 + 8);
        *(short8*)(Bs + sr * 40 + sc)     = *(const short8*)(Brow + k0);
        *(short8*)(Bs + sr * 40 + sc + 8) = *(const short8*)(Brow + k0 + 8);
        __syncthreads();
        short8 af[4], bfr[4];
        #pragma unroll
        for (int i = 0; i < 4; ++i) {
            af[i]  = *(const short8*)(As + (wm + i * 16 + lr) * 40 + lk);
            bfr[i] = *(const short8*)(Bs + (wn + i * 16 + lr) * 40 + lk);
        }
        #pragma unroll
        for (int i = 0; i < 4; ++i)
            #pragma unroll
            for (int j = 0; j < 4; ++j)
                acc[i][j] = __builtin_amdgcn_mfma_f32_16x16x32_bf16(af[i], bfr[j], acc[i][j], 0, 0, 0);
    }
    int rb = m0 + wm + (lane >> 4) * 4;
    int cb = n0 + wn + lr;
    #pragma unroll
    for (int i = 0; i < 4; ++i)
        #pragma unroll
        for (int j = 0; j < 4; ++j)
            #pragma unroll
            for (int r = 0; r < 4; ++r) {
                int row = rb + i * 16 + r;
                int col = cb + j * 16;
                float v = acc[i][j][r];
                if (MODE == 0) ((short*)Cp)[(size_t)row * ldc + col] = f2bf(v);
                else if (MODE == 1) ((float*)Cp)[(size_t)row * ldc + col] += v;
                else if (col < NVOCAB) ((float*)Cp)[(size_t)row * NVOCAB + col] = v;
            }
}

// ---------- geglu + qk extraction + V transpose ----------
__global__ __launch_bounds__(256) void k_geglu(const short* __restrict__ h,
        short* __restrict__ cat, short* __restrict__ vT,
        short* __restrict__ qhb, short* __restrict__ khb) {
    __shared__ short vl[64 * 390];
    int tb = blockIdx.x * 64;
    int t = threadIdx.x;
    for (int i = t; i < 64 * 64; i += 256) {
        int row = i >> 6, f = i & 63;
        size_t tok = tb + row;
        short qv = 0, kv = 0;
        if (f < QKD) { qv = h[tok * HN + f]; kv = h[tok * HN + QKD + f]; }
        qhb[tok * 64 + f] = qv;
        khb[tok * 64 + f] = kv;
    }
    for (int i = t; i < 64 * EM; i += 256) {
        int row = i / EM, e = i % EM;
        size_t tok = tb + row;
        float lin = bf2f(h[tok * HN + 2 * QKD + e]);
        float pg  = bf2f(h[tok * HN + 2 * QKD + EM + e]);
        float gel = pg * 0.5f * (1.f + erff(pg * 0.70710678118654752f));
        short bv = f2bf(lin * gel);
        if (e < DM) cat[tok * EM + e] = bv;
        else vl[row * 390 + (e - DM)] = bv;
    }
    __syncthreads();
    for (int i = t; i < DM * 64; i += 256) {
        int feat = i >> 6, tok = i & 63;
        vT[(size_t)feat * TOK + tb + tok] = vl[tok * 390 + feat];
    }
}

// ---------- flash attention v2: 1 WAVE per block, 16 q-rows, full 384-feat PV ----------
// No inter-wave redundancy, no barrier lockstep, defer-max rescale (T13).
__global__ __launch_bounds__(64) void k_flash(const short* __restrict__ qhb,
        const short* __restrict__ khb, const short* __restrict__ vT,
        short* __restrict__ cat) {
    __shared__ __align__(16) short P[16 * 40];
    int bid = blockIdx.x;
    int b = bid & 3, qt = 127 - (bid >> 2);   // big q-tiles launch first
    int tb = b * SEQ;
    int lane = threadIdx.x & 63;
    int lr = lane & 15, lg = lane >> 4;
    int q0 = qt * 16;
    const float scale = 0.14433756729740643f; // 1/sqrt(48)
    const f32x4 vzero = {0.f, 0.f, 0.f, 0.f};

    short8 qf[2];
    #pragma unroll
    for (int ks = 0; ks < 2; ++ks)
        qf[ks] = *(const short8*)(qhb + (size_t)(tb + q0 + lr) * 64 + ks * 32 + lg * 8);

    f32x4 o[24];
    #pragma unroll
    for (int j = 0; j < 24; ++j) o[j] = vzero;
    float mi[4], li[4];
    #pragma unroll
    for (int r = 0; r < 4; ++r) { mi[r] = -1e30f; li[r] = 0.f; }

    int nkb = (q0 >> 5) + 1;
    for (int kb = 0; kb < nkb; ++kb) {
        int kbase = kb * 32;
        f32x4 s0 = vzero, s1 = vzero;
        #pragma unroll
        for (int ks = 0; ks < 2; ++ks) {
            short8 kf0 = *(const short8*)(khb + (size_t)(tb + kbase + lr) * 64 + ks * 32 + lg * 8);
            short8 kf1 = *(const short8*)(khb + (size_t)(tb + kbase + 16 + lr) * 64 + ks * 32 + lg * 8);
            s0 = __builtin_amdgcn_mfma_f32_16x16x32_bf16(qf[ks], kf0, s0, 0, 0, 0);
            s1 = __builtin_amdgcn_mfma_f32_16x16x32_bf16(qf[ks], kf1, s1, 0, 0, 0);
        }
        // scale + causal mask + per-row tile max
        float pmax[4];
        #pragma unroll
        for (int r = 0; r < 4; ++r) {
            int qg = q0 + lg * 4 + r;
            float v0 = s0[r] * scale, v1 = s1[r] * scale;
            if (kbase + lr > qg) v0 = -1e30f;
            if (kbase + 16 + lr > qg) v1 = -1e30f;
            s0[r] = v0; s1[r] = v1;
            float mx = fmaxf(v0, v1);
            #pragma unroll
            for (int d2 = 1; d2 < 16; d2 <<= 1) mx = fmaxf(mx, __shfl_xor(mx, d2));
            pmax[r] = mx;
        }
        // defer-max: only rescale when the running max grew by > 8
        float dmax = fmaxf(fmaxf(pmax[0] - mi[0], pmax[1] - mi[1]),
                           fmaxf(pmax[2] - mi[2], pmax[3] - mi[3]));
        if (!__all(dmax <= 8.f)) {
            float al[4];
            #pragma unroll
            for (int r = 0; r < 4; ++r) {
                float mn = fmaxf(mi[r], pmax[r]);
                al[r] = __expf(mi[r] - mn);
                li[r] *= al[r];
                mi[r] = mn;
            }
            #pragma unroll
            for (int j = 0; j < 24; ++j)
                #pragma unroll
                for (int r = 0; r < 4; ++r) o[j][r] *= al[r];
        }
        #pragma unroll
        for (int r = 0; r < 4; ++r) {
            float p0 = __expf(s0[r] - mi[r]), p1 = __expf(s1[r] - mi[r]);
            float sum = p0 + p1;
            #pragma unroll
            for (int d2 = 1; d2 < 16; d2 <<= 1) sum += __shfl_xor(sum, d2);
            li[r] += sum;
            s0[r] = p0; s1[r] = p1;
        }
        __syncthreads();
        #pragma unroll
        for (int r = 0; r < 4; ++r) {
            P[(lg * 4 + r) * 40 + lr] = f2bf(s0[r]);
            P[(lg * 4 + r) * 40 + 16 + lr] = f2bf(s1[r]);
        }
        __syncthreads();
        short8 pf = *(const short8*)(P + lr * 40 + lg * 8);
        #pragma unroll
        for (int j = 0; j < 24; ++j) {
            short8 vf = *(const short8*)(vT + (size_t)(j * 16 + lr) * TOK + tb + kbase + lg * 8);
            o[j] = __builtin_amdgcn_mfma_f32_16x16x32_bf16(pf, vf, o[j], 0, 0, 0);
        }
    }
    float inv[4];
    #pragma unroll
    for (int r = 0; r < 4; ++r) inv[r] = 1.f / li[r];
    #pragma unroll
    for (int j = 0; j < 24; ++j)
        #pragma unroll
        for (int r = 0; r < 4; ++r) {
            size_t tok = tb + q0 + lg * 4 + r;
            cat[tok * EM + DM + j * 16 + lr] = f2bf(o[j][r] * inv[r]);
        }
}

extern "C" void kernel_launch(void* const* d_in, const int* in_sizes, int n_in,
                              void* d_out, int out_size, void* d_ws, size_t ws_size,
                              hipStream_t stream) {
    const int*   q     = (const int*)d_in[0];
    const float* freqs = (const float*)d_in[1];
    const float* expw  = (const float*)d_in[2];
    const float* projw = (const float*)d_in[3];
    const float* blkg  = (const float*)d_in[4];
    const float* blkb  = (const float*)d_in[5];
    const float* lng   = (const float*)d_in[6];
    const float* lnb   = (const float*)d_in[7];
    const float* outw  = (const float*)d_in[8];
    float* out = (float*)d_out;

    char* p = (char*)d_ws;
    auto alloc = [&](size_t bytes) {
        char* r = p; p += (bytes + 255) & ~(size_t)255; return r;
    };
    float* x   = (float*)alloc((size_t)TOK * DM * 4);
    short* xn  = (short*)alloc((size_t)TOK * DM * 2);
    short* h   = (short*)alloc((size_t)TOK * HN * 2);
    short* cat = (short*)alloc((size_t)TOK * EM * 2);
    short* vT  = (short*)alloc((size_t)DM * TOK * 2);
    short* qhb = (short*)alloc((size_t)TOK * 64 * 2);
    short* khb = (short*)alloc((size_t)TOK * 64 * 2);
    short* ewb = (short*)alloc((size_t)NBLK * HN * DM * 2);
    short* pwb = (short*)alloc((size_t)NBLK * DM * EM * 2);
    short* owb = (short*)alloc((size_t)128 * DM * 2);

    k_cvt_expw<<<2048, 256, 0, stream>>>(expw, ewb);
    k_cvt<<<2048, 256, 0, stream>>>(projw, pwb, NBLK * DM * EM);
    k_cvt_outw<<<192, 256, 0, stream>>>(outw, owb);
    k_embed<<<TOK / 4, 256, 0, stream>>>(q, freqs, lng, lnb, x);

    for (int L = 0; L < NBLK; ++L) {
        k_ln<<<TOK / 4, 256, 0, stream>>>(x, blkg + L * DM, blkb + L * DM, xn);
        k_gemm<0><<<dim3(64, 13), 256, 0, stream>>>(xn, ewb + (size_t)L * HN * DM,
                                                    DM, DM, DM, h, HN);
        k_geglu<<<TOK / 64, 256, 0, stream>>>(h, cat, vT, qhb, khb);
        k_flash<<<512, 64, 0, stream>>>(qhb, khb, vT, cat);
        k_gemm<1><<<dim3(64, 3), 256, 0, stream>>>(cat, pwb + (size_t)L * DM * EM,
                                                   EM, EM, EM, x, DM);
    }
    k_ln<<<TOK / 4, 256, 0, stream>>>(x, lng, lnb, xn);
    k_gemm<2><<<dim3(64, 1), 256, 0, stream>>>(xn, owb, DM, DM, DM, out, NVOCAB);
}

// Round 4
// 1930.608 us; speedup vs baseline: 1.3403x; 1.3042x over previous
//
#include <hip/hip_runtime.h>
#include <hip/hip_bf16.h>

#define TOK 8192
#define DM 384
#define QKD 48
#define EM 768
#define NBLK 8
#define NVOCAB 100
#define SEQ 2048
#define HN 1664
#define HNV 1632
#define CH 16          // k-tiles (of 32 keys) per split-K chunk = 512 keys
#define NUPB 320       // split-K units per batch
#define NUNITS 1280    // total units (4 batches)

using short8 = __attribute__((ext_vector_type(8))) short;
using f32x4  = __attribute__((ext_vector_type(4))) float;

static __device__ __forceinline__ float bf2f(short s) {
    union { unsigned u; float f; } c; c.u = ((unsigned)(unsigned short)s) << 16; return c.f;
}
static __device__ __forceinline__ short f2bf(float f) {
    union { float f; unsigned u; } c; c.f = f;
    unsigned r = (c.u + 0x7FFFu + ((c.u >> 16) & 1u)) >> 16;
    return (short)r;
}

// ---------- weight conversion ----------
__global__ void k_cvt(const float* __restrict__ s, short* __restrict__ d, int n) {
    for (int i = blockIdx.x * 256 + threadIdx.x; i < n; i += gridDim.x * 256)
        d[i] = f2bf(s[i]);
}
__global__ void k_cvt_expw(const float* __restrict__ s, short* __restrict__ d) {
    const int n = NBLK * HN * DM;
    for (int i = blockIdx.x * 256 + threadIdx.x; i < n; i += gridDim.x * 256) {
        int L = i / (HN * DM); int rem = i % (HN * DM);
        int r = rem / DM; int c = rem % DM;
        float v = (r < HNV) ? s[((size_t)L * HNV + r) * DM + c] : 0.f;
        d[i] = f2bf(v);
    }
}
__global__ void k_cvt_outw(const float* __restrict__ s, short* __restrict__ d) {
    const int n = 128 * DM;
    for (int i = blockIdx.x * 256 + threadIdx.x; i < n; i += gridDim.x * 256) {
        int r = i / DM, c = i % DM;
        d[i] = f2bf(r < NVOCAB ? s[r * DM + c] : 0.f);
    }
}

// ---------- embedding + initial LN ----------
__global__ __launch_bounds__(256) void k_embed(const int* __restrict__ q,
        const float* __restrict__ freqs, const float* __restrict__ lng,
        const float* __restrict__ lnb, float* __restrict__ x) {
    int wid = blockIdx.x * 4 + (threadIdx.x >> 6);
    int lane = threadIdx.x & 63;
    if (wid >= TOK) return;
    float qv = (float)q[wid];
    float v[6]; float s = 0.f, s2 = 0.f;
    #pragma unroll
    for (int i = 0; i < 6; ++i) {
        int d = lane + 64 * i;
        float val;
        if (d < 192) val = sinf(qv * freqs[d]);
        else         val = cosf(qv * freqs[d - 192]);
        v[i] = val; s += val; s2 += val * val;
    }
    #pragma unroll
    for (int m = 1; m < 64; m <<= 1) { s += __shfl_xor(s, m); s2 += __shfl_xor(s2, m); }
    float mean = s * (1.f / DM);
    float var = s2 * (1.f / DM) - mean * mean;
    float rstd = rsqrtf(var + 1e-5f);
    float* xr = x + (size_t)wid * DM;
    #pragma unroll
    for (int i = 0; i < 6; ++i) {
        int d = lane + 64 * i;
        xr[d] = (v[i] - mean) * rstd * lng[d] + lnb[d];
    }
}

// ---------- LayerNorm fp32 -> bf16 ----------
__global__ __launch_bounds__(256) void k_ln(const float* __restrict__ x,
        const float* __restrict__ g, const float* __restrict__ b,
        short* __restrict__ xn) {
    int wid = blockIdx.x * 4 + (threadIdx.x >> 6);
    int lane = threadIdx.x & 63;
    if (wid >= TOK) return;
    const float* xr = x + (size_t)wid * DM;
    float v[6]; float s = 0.f, s2 = 0.f;
    #pragma unroll
    for (int i = 0; i < 6; ++i) {
        v[i] = xr[lane + 64 * i]; s += v[i]; s2 += v[i] * v[i];
    }
    #pragma unroll
    for (int m = 1; m < 64; m <<= 1) { s += __shfl_xor(s, m); s2 += __shfl_xor(s2, m); }
    float mean = s * (1.f / DM);
    float var = s2 * (1.f / DM) - mean * mean;
    float rstd = rsqrtf(var + 1e-5f);
    short* xo = xn + (size_t)wid * DM;
    #pragma unroll
    for (int i = 0; i < 6; ++i) {
        int d = lane + 64 * i;
        xo[d] = f2bf((v[i] - mean) * rstd * g[d] + b[d]);
    }
}

// ---------- GEMM: C[M,N] = A[M,K] @ Bw[N,K]^T, bf16 in, fp32 acc ----------
template<int MODE>
__global__ __launch_bounds__(256) void k_gemm(const short* __restrict__ A,
        const short* __restrict__ Bw, int K, int lda, int ldb,
        void* __restrict__ Cp, int ldc) {
    __shared__ __align__(16) short As[128 * 40];
    __shared__ __align__(16) short Bs[128 * 40];
    int m0 = blockIdx.x * 128, n0 = blockIdx.y * 128;
    int t = threadIdx.x;
    int wid = t >> 6, lane = t & 63;
    int wm = (wid >> 1) * 64, wn = (wid & 1) * 64;
    int lr = lane & 15, lk = (lane >> 4) * 8;
    int sr = t >> 1, sc = (t & 1) * 16;
    const f32x4 vz = {0.f, 0.f, 0.f, 0.f};
    f32x4 acc[4][4];
    #pragma unroll
    for (int i = 0; i < 4; ++i)
        #pragma unroll
        for (int j = 0; j < 4; ++j) acc[i][j] = vz;
    const short* Arow = A + (size_t)(m0 + sr) * lda + sc;
    const short* Brow = Bw + (size_t)(n0 + sr) * ldb + sc;
    for (int k0 = 0; k0 < K; k0 += 32) {
        if (k0) __syncthreads();
        *(short8*)(As + sr * 40 + sc)     = *(const short8*)(Arow + k0);
        *(short8*)(As + sr * 40 + sc + 8) = *(const short8*)(Arow + k0 + 8);
        *(short8*)(Bs + sr * 40 + sc)     = *(const short8*)(Brow + k0);
        *(short8*)(Bs + sr * 40 + sc + 8) = *(const short8*)(Brow + k0 + 8);
        __syncthreads();
        short8 af[4], bfr[4];
        #pragma unroll
        for (int i = 0; i < 4; ++i) {
            af[i]  = *(const short8*)(As + (wm + i * 16 + lr) * 40 + lk);
            bfr[i] = *(const short8*)(Bs + (wn + i * 16 + lr) * 40 + lk);
        }
        #pragma unroll
        for (int i = 0; i < 4; ++i)
            #pragma unroll
            for (int j = 0; j < 4; ++j)
                acc[i][j] = __builtin_amdgcn_mfma_f32_16x16x32_bf16(af[i], bfr[j], acc[i][j], 0, 0, 0);
    }
    int rb = m0 + wm + (lane >> 4) * 4;
    int cb = n0 + wn + lr;
    #pragma unroll
    for (int i = 0; i < 4; ++i)
        #pragma unroll
        for (int j = 0; j < 4; ++j)
            #pragma unroll
            for (int r = 0; r < 4; ++r) {
                int row = rb + i * 16 + r;
                int col = cb + j * 16;
                float v = acc[i][j][r];
                if (MODE == 0) ((short*)Cp)[(size_t)row * ldc + col] = f2bf(v);
                else if (MODE == 1) ((float*)Cp)[(size_t)row * ldc + col] += v;
                else if (col < NVOCAB) ((float*)Cp)[(size_t)row * NVOCAB + col] = v;
            }
}

// ---------- geglu + qk extraction + V transpose ----------
__global__ __launch_bounds__(256) void k_geglu(const short* __restrict__ h,
        short* __restrict__ cat, short* __restrict__ vT,
        short* __restrict__ qhb, short* __restrict__ khb) {
    __shared__ short vl[64 * 390];
    int tb = blockIdx.x * 64;
    int t = threadIdx.x;
    for (int i = t; i < 64 * 64; i += 256) {
        int row = i >> 6, f = i & 63;
        size_t tok = tb + row;
        short qv = 0, kv = 0;
        if (f < QKD) { qv = h[tok * HN + f]; kv = h[tok * HN + QKD + f]; }
        qhb[tok * 64 + f] = qv;
        khb[tok * 64 + f] = kv;
    }
    for (int i = t; i < 64 * EM; i += 256) {
        int row = i / EM, e = i % EM;
        size_t tok = tb + row;
        float lin = bf2f(h[tok * HN + 2 * QKD + e]);
        float pg  = bf2f(h[tok * HN + 2 * QKD + EM + e]);
        float gel = pg * 0.5f * (1.f + erff(pg * 0.70710678118654752f));
        short bv = f2bf(lin * gel);
        if (e < DM) cat[tok * EM + e] = bv;
        else vl[row * 390 + (e - DM)] = bv;
    }
    __syncthreads();
    for (int i = t; i < DM * 64; i += 256) {
        int feat = i >> 6, tok = i & 63;
        vT[(size_t)feat * TOK + tb + tok] = vl[tok * 390 + feat];
    }
}

// ---------- split-K flash: 1 wave per (batch, q-tile, k-chunk of 512 keys) ----------
// Writes unnormalized partial O (bf16) + per-row m,l (fp32).
__global__ __launch_bounds__(64) void k_flash(const short* __restrict__ qhb,
        const short* __restrict__ khb, const short* __restrict__ vT,
        short* __restrict__ Po, float* __restrict__ Pml) {
    __shared__ __align__(16) short P[16 * 40];
    int idx = blockIdx.x;
    int b = idx & 3, u = idx >> 2;
    int g = (u < 32) ? 0 : (u < 96) ? 1 : (u < 192) ? 2 : 3;
    int rem = u - 16 * g * (g + 1);
    int qt = 32 * g + rem / (g + 1);
    int c  = rem % (g + 1);
    int tb = b * SEQ;
    int q0 = qt * 16;
    int nkb = (qt >> 1) + 1;
    int kb0 = c * CH;
    int kb1 = min(kb0 + CH, nkb);
    int lane = threadIdx.x & 63;
    int lr = lane & 15, lg = lane >> 4;
    const float scale = 0.14433756729740643f; // 1/sqrt(48)
    const f32x4 vzero = {0.f, 0.f, 0.f, 0.f};

    short8 qf[2];
    #pragma unroll
    for (int ks = 0; ks < 2; ++ks)
        qf[ks] = *(const short8*)(qhb + (size_t)(tb + q0 + lr) * 64 + ks * 32 + lg * 8);

    f32x4 o[24];
    #pragma unroll
    for (int j = 0; j < 24; ++j) o[j] = vzero;
    float mi[4], li[4];
    #pragma unroll
    for (int r = 0; r < 4; ++r) { mi[r] = -1e30f; li[r] = 0.f; }

    for (int kb = kb0; kb < kb1; ++kb) {
        int kbase = kb * 32;
        // ---- V prefetch: issue all 24 fragment loads before QK/softmax ----
        short8 vf[24];
        #pragma unroll
        for (int j = 0; j < 24; ++j)
            vf[j] = *(const short8*)(vT + (size_t)(j * 16 + lr) * TOK + tb + kbase + lg * 8);

        f32x4 s0 = vzero, s1 = vzero;
        #pragma unroll
        for (int ks = 0; ks < 2; ++ks) {
            short8 kf0 = *(const short8*)(khb + (size_t)(tb + kbase + lr) * 64 + ks * 32 + lg * 8);
            short8 kf1 = *(const short8*)(khb + (size_t)(tb + kbase + 16 + lr) * 64 + ks * 32 + lg * 8);
            s0 = __builtin_amdgcn_mfma_f32_16x16x32_bf16(qf[ks], kf0, s0, 0, 0, 0);
            s1 = __builtin_amdgcn_mfma_f32_16x16x32_bf16(qf[ks], kf1, s1, 0, 0, 0);
        }
        bool needmask = (kbase + 31 > q0);
        float pmax[4];
        #pragma unroll
        for (int r = 0; r < 4; ++r) {
            float v0 = s0[r] * scale, v1 = s1[r] * scale;
            if (needmask) {
                int qg = q0 + lg * 4 + r;
                if (kbase + lr > qg) v0 = -1e30f;
                if (kbase + 16 + lr > qg) v1 = -1e30f;
            }
            s0[r] = v0; s1[r] = v1;
            float mx = fmaxf(v0, v1);
            #pragma unroll
            for (int d2 = 1; d2 < 16; d2 <<= 1) mx = fmaxf(mx, __shfl_xor(mx, d2));
            pmax[r] = mx;
        }
        float dmax = fmaxf(fmaxf(pmax[0] - mi[0], pmax[1] - mi[1]),
                           fmaxf(pmax[2] - mi[2], pmax[3] - mi[3]));
        if (!__all(dmax <= 8.f)) {
            float al[4];
            #pragma unroll
            for (int r = 0; r < 4; ++r) {
                float mn = fmaxf(mi[r], pmax[r]);
                al[r] = __expf(mi[r] - mn);
                li[r] *= al[r];
                mi[r] = mn;
            }
            #pragma unroll
            for (int j = 0; j < 24; ++j)
                #pragma unroll
                for (int r = 0; r < 4; ++r) o[j][r] *= al[r];
        }
        #pragma unroll
        for (int r = 0; r < 4; ++r) {
            float p0 = __expf(s0[r] - mi[r]), p1 = __expf(s1[r] - mi[r]);
            float sum = p0 + p1;
            #pragma unroll
            for (int d2 = 1; d2 < 16; d2 <<= 1) sum += __shfl_xor(sum, d2);
            li[r] += sum;
            s0[r] = p0; s1[r] = p1;
        }
        __syncthreads();
        #pragma unroll
        for (int r = 0; r < 4; ++r) {
            P[(lg * 4 + r) * 40 + lr] = f2bf(s0[r]);
            P[(lg * 4 + r) * 40 + 16 + lr] = f2bf(s1[r]);
        }
        __syncthreads();
        short8 pf = *(const short8*)(P + lr * 40 + lg * 8);
        #pragma unroll
        for (int j = 0; j < 24; ++j)
            o[j] = __builtin_amdgcn_mfma_f32_16x16x32_bf16(pf, vf[j], o[j], 0, 0, 0);
    }
    // ---- write partials (unnormalized) ----
    size_t ob = (size_t)idx * (16 * 384);
    #pragma unroll
    for (int j = 0; j < 24; ++j)
        #pragma unroll
        for (int r = 0; r < 4; ++r)
            Po[ob + (size_t)(lg * 4 + r) * 384 + j * 16 + lr] = f2bf(o[j][r]);
    if (lr == 0) {
        #pragma unroll
        for (int r = 0; r < 4; ++r) {
            Pml[idx * 32 + lg * 4 + r]      = mi[r];
            Pml[idx * 32 + 16 + lg * 4 + r] = li[r];
        }
    }
}

// ---------- combine split-K partials -> cat[:, 384:768] ----------
__global__ __launch_bounds__(256) void k_comb(const short* __restrict__ Po,
        const float* __restrict__ Pml, short* __restrict__ cat) {
    int bid = blockIdx.x;             // 512 = 4 batches x 128 q-tiles
    int b = bid & 3, qt = bid >> 2;
    int g = qt >> 5;
    int nch = g + 1;
    int u0 = 16 * g * (g + 1) + (qt - 32 * g) * (g + 1);
    int tid = threadIdx.x;
    int row = tid >> 4;
    int c0 = (tid & 15) * 24;
    float m[4], l[4], w[4];
    float M = -1e30f;
    #pragma unroll
    for (int c = 0; c < 4; ++c) {
        if (c < nch) {
            int uu = ((u0 + c) << 2) | b;
            m[c] = Pml[uu * 32 + row];
            l[c] = Pml[uu * 32 + 16 + row];
            M = fmaxf(M, m[c]);
        } else { m[c] = -1e30f; l[c] = 0.f; }
    }
    float L = 0.f;
    #pragma unroll
    for (int c = 0; c < 4; ++c) { w[c] = __expf(m[c] - M); L += l[c] * w[c]; }
    float invL = 1.f / L;
    float acc[24];
    #pragma unroll
    for (int e = 0; e < 24; ++e) acc[e] = 0.f;
    #pragma unroll
    for (int c = 0; c < 4; ++c) {
        if (c < nch) {
            int uu = ((u0 + c) << 2) | b;
            const short8* pp = (const short8*)(Po + ((size_t)uu * 16 + row) * 384 + c0);
            #pragma unroll
            for (int v = 0; v < 3; ++v) {
                short8 tv = pp[v];
                #pragma unroll
                for (int k = 0; k < 8; ++k) acc[v * 8 + k] += w[c] * bf2f(tv[k]);
            }
        }
    }
    size_t tok = (size_t)b * SEQ + qt * 16 + row;
    #pragma unroll
    for (int e = 0; e < 24; ++e)
        cat[tok * EM + DM + c0 + e] = f2bf(acc[e] * invL);
}

extern "C" void kernel_launch(void* const* d_in, const int* in_sizes, int n_in,
                              void* d_out, int out_size, void* d_ws, size_t ws_size,
                              hipStream_t stream) {
    const int*   q     = (const int*)d_in[0];
    const float* freqs = (const float*)d_in[1];
    const float* expw  = (const float*)d_in[2];
    const float* projw = (const float*)d_in[3];
    const float* blkg  = (const float*)d_in[4];
    const float* blkb  = (const float*)d_in[5];
    const float* lng   = (const float*)d_in[6];
    const float* lnb   = (const float*)d_in[7];
    const float* outw  = (const float*)d_in[8];
    float* out = (float*)d_out;

    char* p = (char*)d_ws;
    auto alloc = [&](size_t bytes) {
        char* r = p; p += (bytes + 255) & ~(size_t)255; return r;
    };
    float* x   = (float*)alloc((size_t)TOK * DM * 4);
    short* xn  = (short*)alloc((size_t)TOK * DM * 2);
    short* h   = (short*)alloc((size_t)TOK * HN * 2);
    short* cat = (short*)alloc((size_t)TOK * EM * 2);
    short* vT  = (short*)alloc((size_t)DM * TOK * 2);
    short* qhb = (short*)alloc((size_t)TOK * 64 * 2);
    short* khb = (short*)alloc((size_t)TOK * 64 * 2);
    short* ewb = (short*)alloc((size_t)NBLK * HN * DM * 2);
    short* pwb = (short*)alloc((size_t)NBLK * DM * EM * 2);
    short* owb = (short*)alloc((size_t)128 * DM * 2);
    // split-K partials alias the (dead-during-attention) h buffer
    short* Po  = h;                                        // 1280*16*384*2 = 15.73 MB
    float* Pml = (float*)(h + (size_t)NUNITS * 16 * 384);  // 1280*32*4 = 164 KB

    k_cvt_expw<<<2048, 256, 0, stream>>>(expw, ewb);
    k_cvt<<<2048, 256, 0, stream>>>(projw, pwb, NBLK * DM * EM);
    k_cvt_outw<<<192, 256, 0, stream>>>(outw, owb);
    k_embed<<<TOK / 4, 256, 0, stream>>>(q, freqs, lng, lnb, x);

    for (int L = 0; L < NBLK; ++L) {
        k_ln<<<TOK / 4, 256, 0, stream>>>(x, blkg + L * DM, blkb + L * DM, xn);
        k_gemm<0><<<dim3(64, 13), 256, 0, stream>>>(xn, ewb + (size_t)L * HN * DM,
                                                    DM, DM, DM, h, HN);
        k_geglu<<<TOK / 64, 256, 0, stream>>>(h, cat, vT, qhb, khb);
        k_flash<<<NUNITS, 64, 0, stream>>>(qhb, khb, vT, Po, Pml);
        k_comb<<<512, 256, 0, stream>>>(Po, Pml, cat);
        k_gemm<1><<<dim3(64, 3), 256, 0, stream>>>(cat, pwb + (size_t)L * DM * EM,
                                                   EM, EM, EM, x, DM);
    }
    k_ln<<<TOK / 4, 256, 0, stream>>>(x, lng, lnb, xn);
    k_gemm<2><<<dim3(64, 1), 256, 0, stream>>>(xn, owb, DM, DM, DM, out, NVOCAB);
}

// Round 5
// 1815.260 us; speedup vs baseline: 1.4254x; 1.0635x over previous
//
#include <hip/hip_runtime.h>
#include <hip/hip_bf16.h>

#define TOK 8192
#define DM 384
#define QKD 48
#define EM 768
#define NBLK 8
#define NVOCAB 100
#define SEQ 2048
#define HN 1664
#define HNV 1632
#define CH 8           // k-tiles (32 keys) per split-K chunk = 256 keys
#define NUNITS 2304    // compact split-K units (4 batches x 576)

using short8 = __attribute__((ext_vector_type(8))) short;
using f32x4  = __attribute__((ext_vector_type(4))) float;

static __device__ __forceinline__ float bf2f(short s) {
    union { unsigned u; float f; } c; c.u = ((unsigned)(unsigned short)s) << 16; return c.f;
}
static __device__ __forceinline__ short f2bf(float f) {
    union { float f; unsigned u; } c; c.f = f;
    unsigned r = (c.u + 0x7FFFu + ((c.u >> 16) & 1u)) >> 16;
    return (short)r;
}
static __device__ __forceinline__ void gload_lds16(const short* g, short* l) {
    __builtin_amdgcn_global_load_lds((const __attribute__((address_space(1))) void*)g,
                                     (__attribute__((address_space(3))) void*)l, 16, 0, 0);
}

// ---------- weight conversion ----------
__global__ void k_cvt(const float* __restrict__ s, short* __restrict__ d, int n) {
    for (int i = blockIdx.x * 256 + threadIdx.x; i < n; i += gridDim.x * 256)
        d[i] = f2bf(s[i]);
}
__global__ void k_cvt_expw(const float* __restrict__ s, short* __restrict__ d) {
    const int n = NBLK * HN * DM;
    for (int i = blockIdx.x * 256 + threadIdx.x; i < n; i += gridDim.x * 256) {
        int L = i / (HN * DM); int rem = i % (HN * DM);
        int r = rem / DM; int c = rem % DM;
        float v = (r < HNV) ? s[((size_t)L * HNV + r) * DM + c] : 0.f;
        d[i] = f2bf(v);
    }
}
__global__ void k_cvt_outw(const float* __restrict__ s, short* __restrict__ d) {
    const int n = 128 * DM;
    for (int i = blockIdx.x * 256 + threadIdx.x; i < n; i += gridDim.x * 256) {
        int r = i / DM, c = i % DM;
        d[i] = f2bf(r < NVOCAB ? s[r * DM + c] : 0.f);
    }
}

// ---------- embedding + initial LN ----------
__global__ __launch_bounds__(256) void k_embed(const int* __restrict__ q,
        const float* __restrict__ freqs, const float* __restrict__ lng,
        const float* __restrict__ lnb, float* __restrict__ x) {
    int wid = blockIdx.x * 4 + (threadIdx.x >> 6);
    int lane = threadIdx.x & 63;
    if (wid >= TOK) return;
    float qv = (float)q[wid];
    float v[6]; float s = 0.f, s2 = 0.f;
    #pragma unroll
    for (int i = 0; i < 6; ++i) {
        int d = lane + 64 * i;
        float val;
        if (d < 192) val = sinf(qv * freqs[d]);
        else         val = cosf(qv * freqs[d - 192]);
        v[i] = val; s += val; s2 += val * val;
    }
    #pragma unroll
    for (int m = 1; m < 64; m <<= 1) { s += __shfl_xor(s, m); s2 += __shfl_xor(s2, m); }
    float mean = s * (1.f / DM);
    float var = s2 * (1.f / DM) - mean * mean;
    float rstd = rsqrtf(var + 1e-5f);
    float* xr = x + (size_t)wid * DM;
    #pragma unroll
    for (int i = 0; i < 6; ++i) {
        int d = lane + 64 * i;
        xr[d] = (v[i] - mean) * rstd * lng[d] + lnb[d];
    }
}

// ---------- LayerNorm fp32 -> bf16 ----------
__global__ __launch_bounds__(256) void k_ln(const float* __restrict__ x,
        const float* __restrict__ g, const float* __restrict__ b,
        short* __restrict__ xn) {
    int wid = blockIdx.x * 4 + (threadIdx.x >> 6);
    int lane = threadIdx.x & 63;
    if (wid >= TOK) return;
    const float* xr = x + (size_t)wid * DM;
    float v[6]; float s = 0.f, s2 = 0.f;
    #pragma unroll
    for (int i = 0; i < 6; ++i) {
        v[i] = xr[lane + 64 * i]; s += v[i]; s2 += v[i] * v[i];
    }
    #pragma unroll
    for (int m = 1; m < 64; m <<= 1) { s += __shfl_xor(s, m); s2 += __shfl_xor(s2, m); }
    float mean = s * (1.f / DM);
    float var = s2 * (1.f / DM) - mean * mean;
    float rstd = rsqrtf(var + 1e-5f);
    short* xo = xn + (size_t)wid * DM;
    #pragma unroll
    for (int i = 0; i < 6; ++i) {
        int d = lane + 64 * i;
        xo[d] = f2bf((v[i] - mean) * rstd * g[d] + b[d]);
    }
}

// ---------- GEMM: C[M,N] = A[M,K] @ Bw[N,K]^T, bf16 in, fp32 acc ----------
// global_load_lds(16B) staging, XOR-swizzled (s(row)=(row+(row>>2))&3, 2-way free).
template<int MODE>
__global__ __launch_bounds__(256) void k_gemm(const short* __restrict__ A,
        const short* __restrict__ Bw, int K, int lda, int ldb,
        void* __restrict__ Cp, int ldc) {
    __shared__ __align__(16) short As[128 * 32];
    __shared__ __align__(16) short Bs[128 * 32];
    int m0 = blockIdx.x * 128, n0 = blockIdx.y * 128;
    int t = threadIdx.x;
    int wid = t >> 6, lane = t & 63;
    int wm = (wid >> 1) * 64, wn = (wid & 1) * 64;
    int lr = lane & 15, lg = lane >> 4;
    // staging geometry: wave stages 2 segments of 16 rows each (A and B)
    int seg0 = wid * 2, seg1 = wid * 2 + 1;
    int row0 = seg0 * 16 + (lane >> 2), row1 = seg1 * 16 + (lane >> 2);
    int cu0 = (lane & 3) ^ ((row0 + (row0 >> 2)) & 3);
    int cu1 = (lane & 3) ^ ((row1 + (row1 >> 2)) & 3);
    const short* srcA0 = A + (size_t)(m0 + row0) * lda + cu0 * 8;
    const short* srcA1 = A + (size_t)(m0 + row1) * lda + cu1 * 8;
    const short* srcB0 = Bw + (size_t)(n0 + row0) * ldb + cu0 * 8;
    const short* srcB1 = Bw + (size_t)(n0 + row1) * ldb + cu1 * 8;
    short* dA0 = As + seg0 * 512; short* dA1 = As + seg1 * 512;
    short* dB0 = Bs + seg0 * 512; short* dB1 = Bs + seg1 * 512;
    const f32x4 vz = {0.f, 0.f, 0.f, 0.f};
    f32x4 acc[4][4];
    #pragma unroll
    for (int i = 0; i < 4; ++i)
        #pragma unroll
        for (int j = 0; j < 4; ++j) acc[i][j] = vz;
    for (int k0 = 0; k0 < K; k0 += 32) {
        if (k0) __syncthreads();
        gload_lds16(srcA0 + k0, dA0);
        gload_lds16(srcA1 + k0, dA1);
        gload_lds16(srcB0 + k0, dB0);
        gload_lds16(srcB1 + k0, dB1);
        __syncthreads();
        short8 af[4], bfr[4];
        #pragma unroll
        for (int i = 0; i < 4; ++i) {
            int ra = wm + i * 16 + lr;
            int rb = wn + i * 16 + lr;
            af[i]  = *(const short8*)(As + ra * 32 + ((lg ^ ((ra + (ra >> 2)) & 3)) * 8));
            bfr[i] = *(const short8*)(Bs + rb * 32 + ((lg ^ ((rb + (rb >> 2)) & 3)) * 8));
        }
        #pragma unroll
        for (int i = 0; i < 4; ++i)
            #pragma unroll
            for (int j = 0; j < 4; ++j)
                acc[i][j] = __builtin_amdgcn_mfma_f32_16x16x32_bf16(af[i], bfr[j], acc[i][j], 0, 0, 0);
    }
    int rb = m0 + wm + (lane >> 4) * 4;
    int cb = n0 + wn + lr;
    #pragma unroll
    for (int i = 0; i < 4; ++i)
        #pragma unroll
        for (int j = 0; j < 4; ++j)
            #pragma unroll
            for (int r = 0; r < 4; ++r) {
                int row = rb + i * 16 + r;
                int col = cb + j * 16;
                float v = acc[i][j][r];
                if (MODE == 0) ((short*)Cp)[(size_t)row * ldc + col] = f2bf(v);
                else if (MODE == 1) ((float*)Cp)[(size_t)row * ldc + col] += v;
                else if (col < NVOCAB) ((float*)Cp)[(size_t)row * NVOCAB + col] = v;
            }
}

// ---------- geglu + qk extraction + V transpose ----------
__global__ __launch_bounds__(256) void k_geglu(const short* __restrict__ h,
        short* __restrict__ cat, short* __restrict__ vT,
        short* __restrict__ qhb, short* __restrict__ khb) {
    __shared__ short vl[64 * 390];
    int tb = blockIdx.x * 64;
    int t = threadIdx.x;
    for (int i = t; i < 64 * 64; i += 256) {
        int row = i >> 6, f = i & 63;
        size_t tok = tb + row;
        short qv = 0, kv = 0;
        if (f < QKD) { qv = h[tok * HN + f]; kv = h[tok * HN + QKD + f]; }
        qhb[tok * 64 + f] = qv;
        khb[tok * 64 + f] = kv;
    }
    for (int i = t; i < 64 * EM; i += 256) {
        int row = i / EM, e = i % EM;
        size_t tok = tb + row;
        float lin = bf2f(h[tok * HN + 2 * QKD + e]);
        float pg  = bf2f(h[tok * HN + 2 * QKD + EM + e]);
        float gel = pg * 0.5f * (1.f + erff(pg * 0.70710678118654752f));
        short bv = f2bf(lin * gel);
        if (e < DM) cat[tok * EM + e] = bv;
        else vl[row * 390 + (e - DM)] = bv;
    }
    __syncthreads();
    for (int i = t; i < DM * 64; i += 256) {
        int feat = i >> 6, tok = i & 63;
        vT[(size_t)feat * TOK + tb + tok] = vl[tok * 390 + feat];
    }
}

// ---------- split-K flash: uniform grid, 1 wave per (b, qt, chunk of 256 keys) ----------
__global__ __launch_bounds__(64) void k_flash(const short* __restrict__ qhb,
        const short* __restrict__ khb, const short* __restrict__ vT,
        short* __restrict__ Po, float* __restrict__ Pml) {
    int idx = blockIdx.x;            // 4096 = 4 b x 128 qt x 8 c
    int b = idx & 3, qt = (idx >> 2) & 127, c = idx >> 9;
    int g = qt >> 4;
    if (c > g) return;               // invalid chunk
    __shared__ __align__(16) short P[16 * 40];
    int tb = b * SEQ;
    int q0 = qt * 16;
    int nkb = (qt >> 1) + 1;
    int kb0 = c * CH;
    int kb1 = min(kb0 + CH, nkb);
    int lane = threadIdx.x & 63;
    int lr = lane & 15, lg = lane >> 4;
    const float scale = 0.14433756729740643f; // 1/sqrt(48)
    const f32x4 vzero = {0.f, 0.f, 0.f, 0.f};

    short8 qf[2];
    #pragma unroll
    for (int ks = 0; ks < 2; ++ks)
        qf[ks] = *(const short8*)(qhb + (size_t)(tb + q0 + lr) * 64 + ks * 32 + lg * 8);

    f32x4 o[24];
    #pragma unroll
    for (int j = 0; j < 24; ++j) o[j] = vzero;
    float mi[4], li[4];
    #pragma unroll
    for (int r = 0; r < 4; ++r) { mi[r] = -1e30f; li[r] = 0.f; }

    for (int kb = kb0; kb < kb1; ++kb) {
        int kbase = kb * 32;
        // V prefetch: issue all 24 fragment loads before QK/softmax
        short8 vf[24];
        #pragma unroll
        for (int j = 0; j < 24; ++j)
            vf[j] = *(const short8*)(vT + (size_t)(j * 16 + lr) * TOK + tb + kbase + lg * 8);

        f32x4 s0 = vzero, s1 = vzero;
        #pragma unroll
        for (int ks = 0; ks < 2; ++ks) {
            short8 kf0 = *(const short8*)(khb + (size_t)(tb + kbase + lr) * 64 + ks * 32 + lg * 8);
            short8 kf1 = *(const short8*)(khb + (size_t)(tb + kbase + 16 + lr) * 64 + ks * 32 + lg * 8);
            s0 = __builtin_amdgcn_mfma_f32_16x16x32_bf16(qf[ks], kf0, s0, 0, 0, 0);
            s1 = __builtin_amdgcn_mfma_f32_16x16x32_bf16(qf[ks], kf1, s1, 0, 0, 0);
        }
        bool needmask = (kbase + 31 > q0);
        float pmax[4];
        #pragma unroll
        for (int r = 0; r < 4; ++r) {
            float v0 = s0[r] * scale, v1 = s1[r] * scale;
            if (needmask) {
                int qg = q0 + lg * 4 + r;
                if (kbase + lr > qg) v0 = -1e30f;
                if (kbase + 16 + lr > qg) v1 = -1e30f;
            }
            s0[r] = v0; s1[r] = v1;
            float mx = fmaxf(v0, v1);
            #pragma unroll
            for (int d2 = 1; d2 < 16; d2 <<= 1) mx = fmaxf(mx, __shfl_xor(mx, d2));
            pmax[r] = mx;
        }
        float dmax = fmaxf(fmaxf(pmax[0] - mi[0], pmax[1] - mi[1]),
                           fmaxf(pmax[2] - mi[2], pmax[3] - mi[3]));
        if (!__all(dmax <= 8.f)) {
            float al[4];
            #pragma unroll
            for (int r = 0; r < 4; ++r) {
                float mn = fmaxf(mi[r], pmax[r]);
                al[r] = __expf(mi[r] - mn);
                li[r] *= al[r];
                mi[r] = mn;
            }
            #pragma unroll
            for (int j = 0; j < 24; ++j)
                #pragma unroll
                for (int r = 0; r < 4; ++r) o[j][r] *= al[r];
        }
        #pragma unroll
        for (int r = 0; r < 4; ++r) {
            s0[r] = __expf(s0[r] - mi[r]);
            s1[r] = __expf(s1[r] - mi[r]);
        }
        __syncthreads();
        #pragma unroll
        for (int r = 0; r < 4; ++r) {
            P[(lg * 4 + r) * 40 + lr] = f2bf(s0[r]);
            P[(lg * 4 + r) * 40 + 16 + lr] = f2bf(s1[r]);
        }
        __syncthreads();
        short8 pf = *(const short8*)(P + lr * 40 + lg * 8);
        #pragma unroll
        for (int j = 0; j < 24; ++j)
            o[j] = __builtin_amdgcn_mfma_f32_16x16x32_bf16(pf, vf[j], o[j], 0, 0, 0);
        // li sum reduction AFTER PV issue (off critical path)
        #pragma unroll
        for (int r = 0; r < 4; ++r) {
            float sum = s0[r] + s1[r];
            #pragma unroll
            for (int d2 = 1; d2 < 16; d2 <<= 1) sum += __shfl_xor(sum, d2);
            li[r] += sum;
        }
    }
    // write partials (unnormalized) at compact storage id
    int uid = 8 * g * (g + 1) + (qt & 15) * (g + 1) + c;
    int sidx = (uid << 2) | b;
    size_t ob = (size_t)sidx * (16 * 384);
    #pragma unroll
    for (int j = 0; j < 24; ++j)
        #pragma unroll
        for (int r = 0; r < 4; ++r)
            Po[ob + (size_t)(lg * 4 + r) * 384 + j * 16 + lr] = f2bf(o[j][r]);
    if (lr == 0) {
        #pragma unroll
        for (int r = 0; r < 4; ++r) {
            Pml[sidx * 32 + lg * 4 + r]      = mi[r];
            Pml[sidx * 32 + 16 + lg * 4 + r] = li[r];
        }
    }
}

// ---------- combine split-K partials -> cat[:, 384:768] ----------
__global__ __launch_bounds__(256) void k_comb(const short* __restrict__ Po,
        const float* __restrict__ Pml, short* __restrict__ cat) {
    int bid = blockIdx.x;             // 512 = 4 batches x 128 q-tiles
    int b = bid & 3, qt = bid >> 2;
    int g = qt >> 4;
    int nch = g + 1;
    int ubase = 8 * g * (g + 1) + (qt & 15) * (g + 1);
    int tid = threadIdx.x;
    int row = tid >> 4;
    int c0 = (tid & 15) * 24;
    float m[8], l[8], w[8];
    float M = -1e30f;
    #pragma unroll
    for (int c = 0; c < 8; ++c) {
        if (c < nch) {
            int uu = ((ubase + c) << 2) | b;
            m[c] = Pml[uu * 32 + row];
            l[c] = Pml[uu * 32 + 16 + row];
            M = fmaxf(M, m[c]);
        } else { m[c] = -1e30f; l[c] = 0.f; }
    }
    float L = 0.f;
    #pragma unroll
    for (int c = 0; c < 8; ++c) { w[c] = __expf(m[c] - M); L += l[c] * w[c]; }
    float invL = 1.f / L;
    float acc[24];
    #pragma unroll
    for (int e = 0; e < 24; ++e) acc[e] = 0.f;
    #pragma unroll
    for (int c = 0; c < 8; ++c) {
        if (c < nch) {
            int uu = ((ubase + c) << 2) | b;
            const short8* pp = (const short8*)(Po + ((size_t)uu * 16 + row) * 384 + c0);
            #pragma unroll
            for (int v = 0; v < 3; ++v) {
                short8 tv = pp[v];
                #pragma unroll
                for (int k = 0; k < 8; ++k) acc[v * 8 + k] += w[c] * bf2f(tv[k]);
            }
        }
    }
    size_t tok = (size_t)b * SEQ + qt * 16 + row;
    #pragma unroll
    for (int e = 0; e < 24; ++e)
        cat[tok * EM + DM + c0 + e] = f2bf(acc[e] * invL);
}

extern "C" void kernel_launch(void* const* d_in, const int* in_sizes, int n_in,
                              void* d_out, int out_size, void* d_ws, size_t ws_size,
                              hipStream_t stream) {
    const int*   q     = (const int*)d_in[0];
    const float* freqs = (const float*)d_in[1];
    const float* expw  = (const float*)d_in[2];
    const float* projw = (const float*)d_in[3];
    const float* blkg  = (const float*)d_in[4];
    const float* blkb  = (const float*)d_in[5];
    const float* lng   = (const float*)d_in[6];
    const float* lnb   = (const float*)d_in[7];
    const float* outw  = (const float*)d_in[8];
    float* out = (float*)d_out;

    char* p = (char*)d_ws;
    auto alloc = [&](size_t bytes) {
        char* r = p; p += (bytes + 255) & ~(size_t)255; return r;
    };
    float* x   = (float*)alloc((size_t)TOK * DM * 4);
    short* xn  = (short*)alloc((size_t)TOK * DM * 2);
    short* h   = (short*)alloc((size_t)TOK * HN * 2);
    short* cat = (short*)alloc((size_t)TOK * EM * 2);
    short* vT  = (short*)alloc((size_t)DM * TOK * 2);
    short* qhb = (short*)alloc((size_t)TOK * 64 * 2);
    short* khb = (short*)alloc((size_t)TOK * 64 * 2);
    short* ewb = (short*)alloc((size_t)NBLK * HN * DM * 2);
    short* pwb = (short*)alloc((size_t)NBLK * DM * EM * 2);
    short* owb = (short*)alloc((size_t)128 * DM * 2);
    // split-K partials alias the (dead-during-attention) xn+h region (33.5 MB)
    short* Po  = xn;                                       // 2304*16*384*2 = 28.3 MB
    float* Pml = (float*)(Po + (size_t)NUNITS * 16 * 384); // 2304*32*4 = 294 KB

    k_cvt_expw<<<2048, 256, 0, stream>>>(expw, ewb);
    k_cvt<<<2048, 256, 0, stream>>>(projw, pwb, NBLK * DM * EM);
    k_cvt_outw<<<192, 256, 0, stream>>>(outw, owb);
    k_embed<<<TOK / 4, 256, 0, stream>>>(q, freqs, lng, lnb, x);

    for (int L = 0; L < NBLK; ++L) {
        k_ln<<<TOK / 4, 256, 0, stream>>>(x, blkg + L * DM, blkb + L * DM, xn);
        k_gemm<0><<<dim3(64, 13), 256, 0, stream>>>(xn, ewb + (size_t)L * HN * DM,
                                                    DM, DM, DM, h, HN);
        k_geglu<<<TOK / 64, 256, 0, stream>>>(h, cat, vT, qhb, khb);
        k_flash<<<4096, 64, 0, stream>>>(qhb, khb, vT, Po, Pml);
        k_comb<<<512, 256, 0, stream>>>(Po, Pml, cat);
        k_gemm<1><<<dim3(64, 3), 256, 0, stream>>>(cat, pwb + (size_t)L * DM * EM,
                                                   EM, EM, EM, x, DM);
    }
    k_ln<<<TOK / 4, 256, 0, stream>>>(x, lng, lnb, xn);
    k_gemm<2><<<dim3(64, 1), 256, 0, stream>>>(xn, owb, DM, DM, DM, out, NVOCAB);
}

// Round 6
// 1246.548 us; speedup vs baseline: 2.0758x; 1.4562x over previous
//
#include <hip/hip_runtime.h>
#include <hip/hip_bf16.h>

#define TOK 8192
#define DM 384
#define QKD 48
#define EM 768
#define NBLK 8
#define NVOCAB 100
#define SEQ 2048
#define HN 1664
#define HNV 1632
#define CH 8           // k-tiles (32 keys) per split-K chunk = 256 keys
#define NUNITS 2304    // compact split-K units (4 batches x 576)

using short8 = __attribute__((ext_vector_type(8))) short;
using f32x4  = __attribute__((ext_vector_type(4))) float;

static __device__ __forceinline__ float bf2f(short s) {
    union { unsigned u; float f; } c; c.u = ((unsigned)(unsigned short)s) << 16; return c.f;
}
static __device__ __forceinline__ short f2bf(float f) {
    union { float f; unsigned u; } c; c.f = f;
    unsigned r = (c.u + 0x7FFFu + ((c.u >> 16) & 1u)) >> 16;
    return (short)r;
}
static __device__ __forceinline__ void gload_lds16(const short* g, short* l) {
    __builtin_amdgcn_global_load_lds((const __attribute__((address_space(1))) void*)g,
                                     (__attribute__((address_space(3))) void*)l, 16, 0, 0);
}

// ---------- weight conversion ----------
__global__ void k_cvt(const float* __restrict__ s, short* __restrict__ d, int n) {
    for (int i = blockIdx.x * 256 + threadIdx.x; i < n; i += gridDim.x * 256)
        d[i] = f2bf(s[i]);
}
__global__ void k_cvt_expw(const float* __restrict__ s, short* __restrict__ d) {
    const int n = NBLK * HN * DM;
    for (int i = blockIdx.x * 256 + threadIdx.x; i < n; i += gridDim.x * 256) {
        int L = i / (HN * DM); int rem = i % (HN * DM);
        int r = rem / DM; int c = rem % DM;
        float v = (r < HNV) ? s[((size_t)L * HNV + r) * DM + c] : 0.f;
        d[i] = f2bf(v);
    }
}
__global__ void k_cvt_outw(const float* __restrict__ s, short* __restrict__ d) {
    const int n = 128 * DM;
    for (int i = blockIdx.x * 256 + threadIdx.x; i < n; i += gridDim.x * 256) {
        int r = i / DM, c = i % DM;
        d[i] = f2bf(r < NVOCAB ? s[r * DM + c] : 0.f);
    }
}

// ---------- embedding + initial LN ----------
__global__ __launch_bounds__(256) void k_embed(const int* __restrict__ q,
        const float* __restrict__ freqs, const float* __restrict__ lng,
        const float* __restrict__ lnb, float* __restrict__ x) {
    int wid = blockIdx.x * 4 + (threadIdx.x >> 6);
    int lane = threadIdx.x & 63;
    if (wid >= TOK) return;
    float qv = (float)q[wid];
    float v[6]; float s = 0.f, s2 = 0.f;
    #pragma unroll
    for (int i = 0; i < 6; ++i) {
        int d = lane + 64 * i;
        float val;
        if (d < 192) val = sinf(qv * freqs[d]);
        else         val = cosf(qv * freqs[d - 192]);
        v[i] = val; s += val; s2 += val * val;
    }
    #pragma unroll
    for (int m = 1; m < 64; m <<= 1) { s += __shfl_xor(s, m); s2 += __shfl_xor(s2, m); }
    float mean = s * (1.f / DM);
    float var = s2 * (1.f / DM) - mean * mean;
    float rstd = rsqrtf(var + 1e-5f);
    float* xr = x + (size_t)wid * DM;
    #pragma unroll
    for (int i = 0; i < 6; ++i) {
        int d = lane + 64 * i;
        xr[d] = (v[i] - mean) * rstd * lng[d] + lnb[d];
    }
}

// ---------- LayerNorm fp32 -> bf16 ----------
__global__ __launch_bounds__(256) void k_ln(const float* __restrict__ x,
        const float* __restrict__ g, const float* __restrict__ b,
        short* __restrict__ xn) {
    int wid = blockIdx.x * 4 + (threadIdx.x >> 6);
    int lane = threadIdx.x & 63;
    if (wid >= TOK) return;
    const float* xr = x + (size_t)wid * DM;
    float v[6]; float s = 0.f, s2 = 0.f;
    #pragma unroll
    for (int i = 0; i < 6; ++i) {
        v[i] = xr[lane + 64 * i]; s += v[i]; s2 += v[i] * v[i];
    }
    #pragma unroll
    for (int m = 1; m < 64; m <<= 1) { s += __shfl_xor(s, m); s2 += __shfl_xor(s2, m); }
    float mean = s * (1.f / DM);
    float var = s2 * (1.f / DM) - mean * mean;
    float rstd = rsqrtf(var + 1e-5f);
    short* xo = xn + (size_t)wid * DM;
    #pragma unroll
    for (int i = 0; i < 6; ++i) {
        int d = lane + 64 * i;
        xo[d] = f2bf((v[i] - mean) * rstd * g[d] + b[d]);
    }
}

// ---------- GEMM: C[M,N] = A[M,K] @ Bw[N,K]^T, bf16 in, fp32 acc ----------
// global_load_lds(16B) staging, XOR-swizzled (s(row)=(row+(row>>2))&3, 2-way free).
template<int MODE>
__global__ __launch_bounds__(256) void k_gemm(const short* __restrict__ A,
        const short* __restrict__ Bw, int K, int lda, int ldb,
        void* __restrict__ Cp, int ldc) {
    __shared__ __align__(16) short As[128 * 32];
    __shared__ __align__(16) short Bs[128 * 32];
    int m0 = blockIdx.x * 128, n0 = blockIdx.y * 128;
    int t = threadIdx.x;
    int wid = t >> 6, lane = t & 63;
    int wm = (wid >> 1) * 64, wn = (wid & 1) * 64;
    int lr = lane & 15, lg = lane >> 4;
    int seg0 = wid * 2, seg1 = wid * 2 + 1;
    int row0 = seg0 * 16 + (lane >> 2), row1 = seg1 * 16 + (lane >> 2);
    int cu0 = (lane & 3) ^ ((row0 + (row0 >> 2)) & 3);
    int cu1 = (lane & 3) ^ ((row1 + (row1 >> 2)) & 3);
    const short* srcA0 = A + (size_t)(m0 + row0) * lda + cu0 * 8;
    const short* srcA1 = A + (size_t)(m0 + row1) * lda + cu1 * 8;
    const short* srcB0 = Bw + (size_t)(n0 + row0) * ldb + cu0 * 8;
    const short* srcB1 = Bw + (size_t)(n0 + row1) * ldb + cu1 * 8;
    short* dA0 = As + seg0 * 512; short* dA1 = As + seg1 * 512;
    short* dB0 = Bs + seg0 * 512; short* dB1 = Bs + seg1 * 512;
    const f32x4 vz = {0.f, 0.f, 0.f, 0.f};
    f32x4 acc[4][4];
    #pragma unroll
    for (int i = 0; i < 4; ++i)
        #pragma unroll
        for (int j = 0; j < 4; ++j) acc[i][j] = vz;
    for (int k0 = 0; k0 < K; k0 += 32) {
        if (k0) __syncthreads();
        gload_lds16(srcA0 + k0, dA0);
        gload_lds16(srcA1 + k0, dA1);
        gload_lds16(srcB0 + k0, dB0);
        gload_lds16(srcB1 + k0, dB1);
        __syncthreads();
        short8 af[4], bfr[4];
        #pragma unroll
        for (int i = 0; i < 4; ++i) {
            int ra = wm + i * 16 + lr;
            int rb = wn + i * 16 + lr;
            af[i]  = *(const short8*)(As + ra * 32 + ((lg ^ ((ra + (ra >> 2)) & 3)) * 8));
            bfr[i] = *(const short8*)(Bs + rb * 32 + ((lg ^ ((rb + (rb >> 2)) & 3)) * 8));
        }
        #pragma unroll
        for (int i = 0; i < 4; ++i)
            #pragma unroll
            for (int j = 0; j < 4; ++j)
                acc[i][j] = __builtin_amdgcn_mfma_f32_16x16x32_bf16(af[i], bfr[j], acc[i][j], 0, 0, 0);
    }
    int rb = m0 + wm + (lane >> 4) * 4;
    int cb = n0 + wn + lr;
    #pragma unroll
    for (int i = 0; i < 4; ++i)
        #pragma unroll
        for (int j = 0; j < 4; ++j)
            #pragma unroll
            for (int r = 0; r < 4; ++r) {
                int row = rb + i * 16 + r;
                int col = cb + j * 16;
                float v = acc[i][j][r];
                if (MODE == 0) ((short*)Cp)[(size_t)row * ldc + col] = f2bf(v);
                else if (MODE == 1) ((float*)Cp)[(size_t)row * ldc + col] += v;
                else if (col < NVOCAB) ((float*)Cp)[(size_t)row * NVOCAB + col] = v;
            }
}

// ---------- geglu v2: grid (128 tok-chunks, 13 feat-chunks), high parallelism ----------
// fc 0..5:  loc features  -> cat[:, fc*64 .. +64)        (direct short8 write)
// fc 6..11: val features  -> vT[fc*64-384 .. ][tok]      (LDS transpose)
// fc 12:    q/k extraction -> qhb, khb
__global__ __launch_bounds__(256) void k_geglu(const short* __restrict__ h,
        short* __restrict__ cat, short* __restrict__ vT,
        short* __restrict__ qhb, short* __restrict__ khb) {
    __shared__ short tile[64 * 65];
    int tb = blockIdx.x * 64;
    int fc = blockIdx.y;
    int t = threadIdx.x;
    if (fc == 12) {
        // q/k extraction: thread t -> token tb + (t>>2), feature seg (t&3)*16
        int row = t >> 2, seg = (t & 3) * 16;
        size_t tok = tb + row;
        const short* hr = h + tok * HN;
        #pragma unroll
        for (int i = 0; i < 16; ++i) {
            int f = seg + i;
            short qv = (f < QKD) ? hr[f] : (short)0;
            short kv = (f < QKD) ? hr[QKD + f] : (short)0;
            qhb[tok * 64 + f] = qv;
            khb[tok * 64 + f] = kv;
        }
        return;
    }
    int e0 = fc * 64;
    bool isval = (e0 >= DM);
    int rowh = t >> 3, c8 = (t & 7) * 8;
    #pragma unroll
    for (int half = 0; half < 2; ++half) {
        int row = rowh + half * 32;
        size_t tok = tb + row;
        const short* hr = h + tok * HN + 2 * QKD;
        short8 lin = *(const short8*)(hr + e0 + c8);
        short8 pg  = *(const short8*)(hr + EM + e0 + c8);
        short ov[8];
        #pragma unroll
        for (int k = 0; k < 8; ++k) {
            float p = bf2f(pg[k]);
            float gel = p * 0.5f * (1.f + erff(p * 0.70710678118654752f));
            ov[k] = f2bf(bf2f(lin[k]) * gel);
        }
        if (!isval) {
            short8 o8;
            #pragma unroll
            for (int k = 0; k < 8; ++k) o8[k] = ov[k];
            *(short8*)(cat + tok * EM + e0 + c8) = o8;
        } else {
            #pragma unroll
            for (int k = 0; k < 8; ++k) tile[row * 65 + c8 + k] = ov[k];
        }
    }
    if (isval) {
        __syncthreads();
        int f0 = e0 - DM;
        int fl = t >> 2, ts = (t & 3) * 16;
        short tmp[16];
        #pragma unroll
        for (int i = 0; i < 16; ++i) tmp[i] = tile[(ts + i) * 65 + fl];
        short8 a, b2;
        #pragma unroll
        for (int i = 0; i < 8; ++i) { a[i] = tmp[i]; b2[i] = tmp[8 + i]; }
        short* dst = vT + (size_t)(f0 + fl) * TOK + tb + ts;
        *(short8*)dst = a;
        *(short8*)(dst + 8) = b2;
    }
}

// ---------- split-K flash: uniform grid, 1 wave per (b, qt, chunk of 256 keys) ----------
__global__ __launch_bounds__(64) void k_flash(const short* __restrict__ qhb,
        const short* __restrict__ khb, const short* __restrict__ vT,
        short* __restrict__ Po, float* __restrict__ Pml) {
    int idx = blockIdx.x;            // 4096 = 4 b x 128 qt x 8 c
    int b = idx & 3, qt = (idx >> 2) & 127, c = idx >> 9;
    int g = qt >> 4;
    if (c > g) return;               // invalid chunk
    __shared__ __align__(16) short P[16 * 40];
    int tb = b * SEQ;
    int q0 = qt * 16;
    int nkb = (qt >> 1) + 1;
    int kb0 = c * CH;
    int kb1 = min(kb0 + CH, nkb);
    int lane = threadIdx.x & 63;
    int lr = lane & 15, lg = lane >> 4;
    const float scale = 0.14433756729740643f; // 1/sqrt(48)
    const f32x4 vzero = {0.f, 0.f, 0.f, 0.f};

    short8 qf[2];
    #pragma unroll
    for (int ks = 0; ks < 2; ++ks)
        qf[ks] = *(const short8*)(qhb + (size_t)(tb + q0 + lr) * 64 + ks * 32 + lg * 8);

    f32x4 o[24];
    #pragma unroll
    for (int j = 0; j < 24; ++j) o[j] = vzero;
    float mi[4], li[4];
    #pragma unroll
    for (int r = 0; r < 4; ++r) { mi[r] = -1e30f; li[r] = 0.f; }

    for (int kb = kb0; kb < kb1; ++kb) {
        int kbase = kb * 32;
        short8 vf[24];
        #pragma unroll
        for (int j = 0; j < 24; ++j)
            vf[j] = *(const short8*)(vT + (size_t)(j * 16 + lr) * TOK + tb + kbase + lg * 8);

        f32x4 s0 = vzero, s1 = vzero;
        #pragma unroll
        for (int ks = 0; ks < 2; ++ks) {
            short8 kf0 = *(const short8*)(khb + (size_t)(tb + kbase + lr) * 64 + ks * 32 + lg * 8);
            short8 kf1 = *(const short8*)(khb + (size_t)(tb + kbase + 16 + lr) * 64 + ks * 32 + lg * 8);
            s0 = __builtin_amdgcn_mfma_f32_16x16x32_bf16(qf[ks], kf0, s0, 0, 0, 0);
            s1 = __builtin_amdgcn_mfma_f32_16x16x32_bf16(qf[ks], kf1, s1, 0, 0, 0);
        }
        bool needmask = (kbase + 31 > q0);
        float pmax[4];
        #pragma unroll
        for (int r = 0; r < 4; ++r) {
            float v0 = s0[r] * scale, v1 = s1[r] * scale;
            if (needmask) {
                int qg = q0 + lg * 4 + r;
                if (kbase + lr > qg) v0 = -1e30f;
                if (kbase + 16 + lr > qg) v1 = -1e30f;
            }
            s0[r] = v0; s1[r] = v1;
            float mx = fmaxf(v0, v1);
            #pragma unroll
            for (int d2 = 1; d2 < 16; d2 <<= 1) mx = fmaxf(mx, __shfl_xor(mx, d2));
            pmax[r] = mx;
        }
        float dmax = fmaxf(fmaxf(pmax[0] - mi[0], pmax[1] - mi[1]),
                           fmaxf(pmax[2] - mi[2], pmax[3] - mi[3]));
        if (!__all(dmax <= 8.f)) {
            float al[4];
            #pragma unroll
            for (int r = 0; r < 4; ++r) {
                float mn = fmaxf(mi[r], pmax[r]);
                al[r] = __expf(mi[r] - mn);
                li[r] *= al[r];
                mi[r] = mn;
            }
            #pragma unroll
            for (int j = 0; j < 24; ++j)
                #pragma unroll
                for (int r = 0; r < 4; ++r) o[j][r] *= al[r];
        }
        #pragma unroll
        for (int r = 0; r < 4; ++r) {
            s0[r] = __expf(s0[r] - mi[r]);
            s1[r] = __expf(s1[r] - mi[r]);
        }
        __syncthreads();
        #pragma unroll
        for (int r = 0; r < 4; ++r) {
            P[(lg * 4 + r) * 40 + lr] = f2bf(s0[r]);
            P[(lg * 4 + r) * 40 + 16 + lr] = f2bf(s1[r]);
        }
        __syncthreads();
        short8 pf = *(const short8*)(P + lr * 40 + lg * 8);
        #pragma unroll
        for (int j = 0; j < 24; ++j)
            o[j] = __builtin_amdgcn_mfma_f32_16x16x32_bf16(pf, vf[j], o[j], 0, 0, 0);
        #pragma unroll
        for (int r = 0; r < 4; ++r) {
            float sum = s0[r] + s1[r];
            #pragma unroll
            for (int d2 = 1; d2 < 16; d2 <<= 1) sum += __shfl_xor(sum, d2);
            li[r] += sum;
        }
    }
    int uid = 8 * g * (g + 1) + (qt & 15) * (g + 1) + c;
    int sidx = (uid << 2) | b;
    size_t ob = (size_t)sidx * (16 * 384);
    #pragma unroll
    for (int j = 0; j < 24; ++j)
        #pragma unroll
        for (int r = 0; r < 4; ++r)
            Po[ob + (size_t)(lg * 4 + r) * 384 + j * 16 + lr] = f2bf(o[j][r]);
    if (lr == 0) {
        #pragma unroll
        for (int r = 0; r < 4; ++r) {
            Pml[sidx * 32 + lg * 4 + r]      = mi[r];
            Pml[sidx * 32 + 16 + lg * 4 + r] = li[r];
        }
    }
}

// ---------- combine split-K partials -> cat[:, 384:768] ----------
__global__ __launch_bounds__(256) void k_comb(const short* __restrict__ Po,
        const float* __restrict__ Pml, short* __restrict__ cat) {
    int bid = blockIdx.x;             // 512 = 4 batches x 128 q-tiles
    int b = bid & 3, qt = bid >> 2;
    int g = qt >> 4;
    int nch = g + 1;
    int ubase = 8 * g * (g + 1) + (qt & 15) * (g + 1);
    int tid = threadIdx.x;
    int row = tid >> 4;
    int c0 = (tid & 15) * 24;
    float m[8], l[8], w[8];
    float M = -1e30f;
    #pragma unroll
    for (int c = 0; c < 8; ++c) {
        if (c < nch) {
            int uu = ((ubase + c) << 2) | b;
            m[c] = Pml[uu * 32 + row];
            l[c] = Pml[uu * 32 + 16 + row];
            M = fmaxf(M, m[c]);
        } else { m[c] = -1e30f; l[c] = 0.f; }
    }
    float L = 0.f;
    #pragma unroll
    for (int c = 0; c < 8; ++c) { w[c] = __expf(m[c] - M); L += l[c] * w[c]; }
    float invL = 1.f / L;
    float acc[24];
    #pragma unroll
    for (int e = 0; e < 24; ++e) acc[e] = 0.f;
    #pragma unroll
    for (int c = 0; c < 8; ++c) {
        if (c < nch) {
            int uu = ((ubase + c) << 2) | b;
            const short8* pp = (const short8*)(Po + ((size_t)uu * 16 + row) * 384 + c0);
            #pragma unroll
            for (int v = 0; v < 3; ++v) {
                short8 tv = pp[v];
                #pragma unroll
                for (int k = 0; k < 8; ++k) acc[v * 8 + k] += w[c] * bf2f(tv[k]);
            }
        }
    }
    size_t tok = (size_t)b * SEQ + qt * 16 + row;
    #pragma unroll
    for (int e = 0; e < 24; ++e)
        cat[tok * EM + DM + c0 + e] = f2bf(acc[e] * invL);
}

extern "C" void kernel_launch(void* const* d_in, const int* in_sizes, int n_in,
                              void* d_out, int out_size, void* d_ws, size_t ws_size,
                              hipStream_t stream) {
    const int*   q     = (const int*)d_in[0];
    const float* freqs = (const float*)d_in[1];
    const float* expw  = (const float*)d_in[2];
    const float* projw = (const float*)d_in[3];
    const float* blkg  = (const float*)d_in[4];
    const float* blkb  = (const float*)d_in[5];
    const float* lng   = (const float*)d_in[6];
    const float* lnb   = (const float*)d_in[7];
    const float* outw  = (const float*)d_in[8];
    float* out = (float*)d_out;

    char* p = (char*)d_ws;
    auto alloc = [&](size_t bytes) {
        char* r = p; p += (bytes + 255) & ~(size_t)255; return r;
    };
    float* x   = (float*)alloc((size_t)TOK * DM * 4);
    short* xn  = (short*)alloc((size_t)TOK * DM * 2);
    short* h   = (short*)alloc((size_t)TOK * HN * 2);
    short* cat = (short*)alloc((size_t)TOK * EM * 2);
    short* vT  = (short*)alloc((size_t)DM * TOK * 2);
    short* qhb = (short*)alloc((size_t)TOK * 64 * 2);
    short* khb = (short*)alloc((size_t)TOK * 64 * 2);
    short* ewb = (short*)alloc((size_t)NBLK * HN * DM * 2);
    short* pwb = (short*)alloc((size_t)NBLK * DM * EM * 2);
    short* owb = (short*)alloc((size_t)128 * DM * 2);
    // split-K partials alias the (dead-during-attention) xn+h region (33.5 MB)
    short* Po  = xn;                                       // 2304*16*384*2 = 28.3 MB
    float* Pml = (float*)(Po + (size_t)NUNITS * 16 * 384); // 2304*32*4 = 294 KB

    k_cvt_expw<<<2048, 256, 0, stream>>>(expw, ewb);
    k_cvt<<<2048, 256, 0, stream>>>(projw, pwb, NBLK * DM * EM);
    k_cvt_outw<<<192, 256, 0, stream>>>(outw, owb);
    k_embed<<<TOK / 4, 256, 0, stream>>>(q, freqs, lng, lnb, x);

    for (int L = 0; L < NBLK; ++L) {
        k_ln<<<TOK / 4, 256, 0, stream>>>(x, blkg + L * DM, blkb + L * DM, xn);
        k_gemm<0><<<dim3(64, 13), 256, 0, stream>>>(xn, ewb + (size_t)L * HN * DM,
                                                    DM, DM, DM, h, HN);
        k_geglu<<<dim3(128, 13), 256, 0, stream>>>(h, cat, vT, qhb, khb);
        k_flash<<<4096, 64, 0, stream>>>(qhb, khb, vT, Po, Pml);
        k_comb<<<512, 256, 0, stream>>>(Po, Pml, cat);
        k_gemm<1><<<dim3(64, 3), 256, 0, stream>>>(cat, pwb + (size_t)L * DM * EM,
                                                   EM, EM, EM, x, DM);
    }
    k_ln<<<TOK / 4, 256, 0, stream>>>(x, lng, lnb, xn);
    k_gemm<2><<<dim3(64, 1), 256, 0, stream>>>(xn, owb, DM, DM, DM, out, NVOCAB);
}